// Round 7
// baseline (375.203 us; speedup 1.0000x reference)
//
#include <hip/hip_runtime.h>
#include <hip/hip_bf16.h>

#define LOG2E 1.44269504088896340736f

typedef __attribute__((ext_vector_type(8))) short short8;
typedef __attribute__((ext_vector_type(4))) float floatx4;

static __device__ __forceinline__ short f2bf(float f) {
    union { float f; unsigned u; } v; v.f = f;
    unsigned r = (v.u + 0x7FFF + ((v.u >> 16) & 1)) >> 16;  // RNE
    return (short)r;
}

static __device__ __forceinline__ floatx4 mfma16(short8 a, short8 b, floatx4 c) {
    return __builtin_amdgcn_mfma_f32_16x16x32_bf16(a, b, c, 0, 0, 0);
}

static __device__ __forceinline__ unsigned cvt_pk_bf16(float lo, float hi) {
    unsigned u;
    asm("v_cvt_pk_bf16_f32 %0, %1, %2" : "=v"(u) : "v"(lo), "v"(hi));
    return u;
}

// ---------------- Weight pre-convert: wb[576][512] bf16 ----------------
__global__ __launch_bounds__(256) void wcvt_kernel(
    const float* __restrict__ wq, const float* __restrict__ wk,
    const float* __restrict__ wv, short* __restrict__ wb)
{
    const int idx = (blockIdx.x * 256 + threadIdx.x) * 4;
    const int row = idx >> 9;
    const int col = idx & 511;
    const float* src;
    float sc = 1.0f;
    if (row < 32)      { src = wq + (size_t)row * 512; sc = LOG2E; }
    else if (row < 64) { src = wk + (size_t)(row - 32) * 512; }
    else               { src = wv + (size_t)(row - 64) * 512; }
    floatx4 v = *(const floatx4*)(src + col);
    union { short s[4]; long long ll; } o;
#pragma unroll
    for (int u = 0; u < 4; u++) o.s[u] = f2bf(v[u] * sc);
    *(long long*)(wb + idx) = o.ll;
}

// ---------------- Projection ----------------
// grid (128 n-tiles of 32, 3 o-groups, B), block 256 (4 waves), LDS 33 KB ->
// 4 blocks/CU. Staging packs c-pairs via cvt_pk -> ds_write_b32.
__global__ __launch_bounds__(256) void proj_kernel(
    const float* __restrict__ x, const short* __restrict__ wb,
    const float* __restrict__ bq, const float* __restrict__ bk,
    const float* __restrict__ bv,
    short* __restrict__ qT, short* __restrict__ kT, short* __restrict__ vm)
{
    __shared__ short xT[32 * 520];   // [n][c] bf16, pitch 520 (1040B, 16B-aligned)
    const int tid = threadIdx.x;
    const int w = tid >> 6;
    const int lane = tid & 63;
    const int l15 = lane & 15, l4 = lane >> 4;
    const int n0 = blockIdx.x * 32;
    const int og = blockIdx.y;       // ot = og*3 .. og*3+2
    const int b  = blockIdx.z;

    const float* xb = x + (size_t)b * 512 * 4096;

    // stage [512c][32n] as bf16 [n][c]: thread = (c-pair, n-pair), b32 writes
#pragma unroll 4
    for (int p = 0; p < 16; p++) {
        const int c  = (p * 16 + (tid >> 4)) * 2;
        const int nr = (tid & 15) * 2;
        const float* r0 = xb + (size_t)c * 4096 + n0 + nr;
        const float* r1 = r0 + 4096;
        float a0 = r0[0], a1 = r0[1];
        float b0 = r1[0], b1 = r1[1];
        *(unsigned*)&xT[nr * 520 + c]       = cvt_pk_bf16(a0, b0);
        *(unsigned*)&xT[(nr + 1) * 520 + c] = cvt_pk_bf16(a1, b1);
    }
    __syncthreads();

#pragma unroll 1
    for (int oi = 0; oi < 3; oi++) {
        const int ot = og * 3 + oi;
        const short* wrow = wb + (size_t)(ot * 64 + w * 16 + l15) * 512;
        floatx4 acc[2];
#pragma unroll
        for (int i = 0; i < 2; i++) acc[i] = (floatx4)(0.0f);

#pragma unroll 4
        for (int c0 = 0; c0 < 512; c0 += 32) {
            short8 af = *(const short8*)(wrow + c0 + 8 * l4);
#pragma unroll
            for (int nt = 0; nt < 2; nt++) {
                short8 bf = *(const short8*)&xT[(nt * 16 + l15) * 520 + c0 + 8 * l4];
                acc[nt] = mfma16(af, bf, acc[nt]);
            }
        }

#pragma unroll
        for (int r = 0; r < 4; r++) {
            const int o_d = ot * 64 + w * 16 + 4 * l4 + r;
#pragma unroll
            for (int nt = 0; nt < 2; nt++) {
                const int n = n0 + nt * 16 + l15;
                const float val = acc[nt][r];
                if (o_d < 32) {
                    qT[((size_t)(b * 4096 + n)) * 32 + o_d] = f2bf(val + bq[o_d] * LOG2E);
                } else if (o_d < 64) {
                    const int s = n & 31;
                    const int p = 16 * ((s >> 2) & 1) + 4 * (s >> 3) + (s & 3);
                    const int nst = (n & ~31) | p;
                    kT[((size_t)(b * 4096 + nst)) * 32 + (o_d - 32)] = f2bf(val + bk[o_d - 32]);
                } else {
                    vm[((size_t)(b * 512 + (o_d - 64))) * 4096 + n] = f2bf(val + bv[o_d - 64]);
                }
            }
        }
    }
}

// ---------------- Flash attention + residual ----------------
// 1024 blocks x 4 waves (256 thr) = exactly 4 blocks/CU = 16 waves/CU.
// Block = (b, c-half, q-tile of 32); wave covers 64 c. j-macro-tile = 128
// (wave w produces j in [w*32,+32)), dbuf P 16 KB, one barrier per tile,
// K prefetched one tile ahead, setprio around PV cluster.
__global__ __launch_bounds__(256) void attn_kernel(
    const short* __restrict__ qT, const short* __restrict__ kT,
    const short* __restrict__ vm, const float* __restrict__ x,
    const float* __restrict__ gamma, float* __restrict__ out)
{
    __shared__ short P_lds[2][8 * 512];    // [buf][frag = w*2+it][lane*8]
    __shared__ float red_lds[4][32];
    const int tid = threadIdx.x;
    const int lane = tid & 63;
    const int w = tid >> 6;
    const int l15 = lane & 15, l4 = lane >> 4;

    // XCD decode: xcd = b*2 + ch -> per-XCD V slice 2 MB (L2-resident)
    const int bid = blockIdx.x;
    const int xcd = bid & 7;
    const int b   = xcd >> 1;
    const int ch  = xcd & 1;
    const int qt  = bid >> 3;          // 0..127
    const int i0  = qt * 32;
    const int cb  = ch * 256 + w * 64;

    short8 qf[2];
#pragma unroll
    for (int it = 0; it < 2; it++)
        qf[it] = *(const short8*)(qT + ((size_t)(b * 4096 + i0 + it * 16 + l15)) * 32 + 8 * l4);

    floatx4 acc[4][2];   // [ct][it]
#pragma unroll
    for (int ct = 0; ct < 4; ct++)
#pragma unroll
        for (int it = 0; it < 2; it++) acc[ct][it] = (floatx4)(0.0f);

    float l_[2] = {0.0f, 0.0f};

    const short* kb = kT + (size_t)b * 4096 * 32;
    const short* vb = vm + (size_t)b * 512 * 4096;

#define PROD(T, KF0, KF1)                                                            \
    {                                                                                \
        const int buf = (T) & 1;                                                     \
        _Pragma("unroll")                                                            \
        for (int it = 0; it < 2; it++) {                                             \
            floatx4 s0 = mfma16((KF0), qf[it], (floatx4)(0.0f));                     \
            floatx4 s1 = mfma16((KF1), qf[it], (floatx4)(0.0f));                     \
            float p[8];                                                              \
            _Pragma("unroll")                                                        \
            for (int r = 0; r < 4; r++) {                                            \
                p[r]     = __builtin_amdgcn_exp2f(s0[r]);                            \
                p[4 + r] = __builtin_amdgcn_exp2f(s1[r]);                            \
            }                                                                        \
            union { short8 s; unsigned u[4]; } pk;                                   \
            _Pragma("unroll")                                                        \
            for (int j2 = 0; j2 < 4; j2++) pk.u[j2] = cvt_pk_bf16(p[2*j2], p[2*j2+1]); \
            *(short8*)&P_lds[buf][(w * 2 + it) * 512 + lane * 8] = pk.s;             \
            l_[it] += ((p[0] + p[1]) + (p[2] + p[3])) + ((p[4] + p[5]) + (p[6] + p[7])); \
        }                                                                            \
    }

#define CONSUME(T)                                                                   \
    {                                                                                \
        const int buf = (T) & 1;                                                     \
        __builtin_amdgcn_s_setprio(1);                                               \
        _Pragma("unroll")                                                            \
        for (int jg = 0; jg < 4; jg++) {                                             \
            short8 pcf[2];                                                           \
            _Pragma("unroll")                                                        \
            for (int it = 0; it < 2; it++)                                           \
                pcf[it] = *(const short8*)&P_lds[buf][(jg * 2 + it) * 512 + lane * 8]; \
            _Pragma("unroll")                                                        \
            for (int ct = 0; ct < 4; ct++) {                                         \
                short8 vf = *(const short8*)(vb + (size_t)(cb + ct * 16 + l15) * 4096 \
                                             + (T) * 128 + jg * 32 + 8 * l4);        \
                _Pragma("unroll")                                                    \
                for (int it = 0; it < 2; it++)                                       \
                    acc[ct][it] = mfma16(vf, pcf[it], acc[ct][it]);                  \
            }                                                                        \
        }                                                                            \
        __builtin_amdgcn_s_setprio(0);                                               \
    }

    short8 kf0 = *(const short8*)(kb + (size_t)(w * 32 + l15) * 32 + 8 * l4);
    short8 kf1 = *(const short8*)(kb + (size_t)(w * 32 + 16 + l15) * 32 + 8 * l4);
    PROD(0, kf0, kf1);

#pragma unroll 1
    for (int t = 0; t < 31; t++) {
        __syncthreads();
        const int jj = (t + 1) * 128 + w * 32;
        short8 nk0 = *(const short8*)(kb + (size_t)(jj + l15) * 32 + 8 * l4);
        short8 nk1 = *(const short8*)(kb + (size_t)(jj + 16 + l15) * 32 + 8 * l4);
        CONSUME(t);
        PROD(t + 1, nk0, nk1);
    }
    __syncthreads();
    CONSUME(31);
#undef PROD
#undef CONSUME

    // l: reduce within wave, then across the 4 producer waves
#pragma unroll
    for (int it = 0; it < 2; it++) {
        l_[it] += __shfl_xor(l_[it], 16, 64);
        l_[it] += __shfl_xor(l_[it], 32, 64);
    }
    if (lane < 16)
#pragma unroll
        for (int it = 0; it < 2; it++) red_lds[w][it * 16 + lane] = l_[it];
    __syncthreads();

    const float g = gamma[0];
    float inv[2];
#pragma unroll
    for (int it = 0; it < 2; it++) {
        float s = 0.0f;
#pragma unroll
        for (int ww = 0; ww < 4; ww++) s += red_lds[ww][it * 16 + l15];
        inv[it] = g / s;
    }

#pragma unroll
    for (int ct = 0; ct < 4; ct++)
#pragma unroll
        for (int it = 0; it < 2; it++)
#pragma unroll
            for (int r = 0; r < 4; r++) {
                const int c = cb + ct * 16 + 4 * l4 + r;
                const int i = i0 + it * 16 + l15;
                const size_t o = ((size_t)(b * 512 + c)) * 4096 + i;
                out[o] = acc[ct][it][r] * inv[it] + x[o];
            }
}

extern "C" void kernel_launch(void* const* d_in, const int* in_sizes, int n_in,
                              void* d_out, int out_size, void* d_ws, size_t ws_size,
                              hipStream_t stream) {
    const float* x     = (const float*)d_in[0];
    const float* wq    = (const float*)d_in[1];
    const float* bq    = (const float*)d_in[2];
    const float* wk    = (const float*)d_in[3];
    const float* bk    = (const float*)d_in[4];
    const float* wv    = (const float*)d_in[5];
    const float* bv    = (const float*)d_in[6];
    const float* gamma = (const float*)d_in[7];
    float* out = (float*)d_out;

    short* qT = (short*)d_ws;                  // 1 MB
    short* kT = qT + (size_t)4 * 4096 * 32;    // 1 MB
    short* vm = kT + (size_t)4 * 4096 * 32;    // 16 MB
    short* wb = vm + (size_t)4 * 512 * 4096;   // 0.56 MB

    wcvt_kernel<<<288, 256, 0, stream>>>(wq, wk, wv, wb);
    proj_kernel<<<dim3(128, 3, 4), 256, 0, stream>>>(x, wb, bq, bk, bv, qT, kT, vm);
    attn_kernel<<<1024, 256, 0, stream>>>(qT, kT, vm, x, gamma, out);
}

// Round 8
// 202.089 us; speedup vs baseline: 1.8566x; 1.8566x over previous
//
#include <hip/hip_runtime.h>
#include <hip/hip_bf16.h>

#define LOG2E 1.44269504088896340736f

typedef __attribute__((ext_vector_type(8))) short short8;
typedef __attribute__((ext_vector_type(4))) float floatx4;

static __device__ __forceinline__ short f2bf(float f) {
    union { float f; unsigned u; } v; v.f = f;
    unsigned r = (v.u + 0x7FFF + ((v.u >> 16) & 1)) >> 16;  // RNE
    return (short)r;
}

static __device__ __forceinline__ floatx4 mfma16(short8 a, short8 b, floatx4 c) {
    return __builtin_amdgcn_mfma_f32_16x16x32_bf16(a, b, c, 0, 0, 0);
}

static __device__ __forceinline__ unsigned cvt_pk_bf16(float lo, float hi) {
    unsigned u;
    asm("v_cvt_pk_bf16_f32 %0, %1, %2" : "=v"(u) : "v"(lo), "v"(hi));
    return u;
}

// ---------------- Weight pre-convert: wb[576][512] bf16 ----------------
__global__ __launch_bounds__(256) void wcvt_kernel(
    const float* __restrict__ wq, const float* __restrict__ wk,
    const float* __restrict__ wv, short* __restrict__ wb)
{
    const int idx = (blockIdx.x * 256 + threadIdx.x) * 4;
    const int row = idx >> 9;
    const int col = idx & 511;
    const float* src;
    float sc = 1.0f;
    if (row < 32)      { src = wq + (size_t)row * 512; sc = LOG2E; }
    else if (row < 64) { src = wk + (size_t)(row - 32) * 512; }
    else               { src = wv + (size_t)(row - 64) * 512; }
    floatx4 v = *(const floatx4*)(src + col);
    union { short s[4]; long long ll; } o;
#pragma unroll
    for (int u = 0; u < 4; u++) o.s[u] = f2bf(v[u] * sc);
    *(long long*)(wb + idx) = o.ll;
}

// ---------------- Projection ----------------
// grid (128 n-tiles of 32, 3 o-groups, B), block 256 (4 waves), LDS 33 KB.
__global__ __launch_bounds__(256) void proj_kernel(
    const float* __restrict__ x, const short* __restrict__ wb,
    const float* __restrict__ bq, const float* __restrict__ bk,
    const float* __restrict__ bv,
    short* __restrict__ qT, short* __restrict__ kT, short* __restrict__ vm)
{
    __shared__ short xT[32 * 520];   // [n][c] bf16
    const int tid = threadIdx.x;
    const int w = tid >> 6;
    const int lane = tid & 63;
    const int l15 = lane & 15, l4 = lane >> 4;
    const int n0 = blockIdx.x * 32;
    const int og = blockIdx.y;       // ot = og*3 .. og*3+2
    const int b  = blockIdx.z;

    const float* xb = x + (size_t)b * 512 * 4096;

#pragma unroll 4
    for (int p = 0; p < 16; p++) {
        const int c = 32 * p + (tid >> 3);
        const int nr = (tid & 7) * 4;
        floatx4 xv = *(const floatx4*)(xb + (size_t)c * 4096 + n0 + nr);
#pragma unroll
        for (int u = 0; u < 4; u++) xT[(nr + u) * 520 + c] = f2bf(xv[u]);
    }
    __syncthreads();

#pragma unroll 1
    for (int oi = 0; oi < 3; oi++) {
        const int ot = og * 3 + oi;
        const short* wrow = wb + (size_t)(ot * 64 + w * 16 + l15) * 512;
        floatx4 acc[2];
#pragma unroll
        for (int i = 0; i < 2; i++) acc[i] = (floatx4)(0.0f);

#pragma unroll 4
        for (int c0 = 0; c0 < 512; c0 += 32) {
            short8 af = *(const short8*)(wrow + c0 + 8 * l4);
#pragma unroll
            for (int nt = 0; nt < 2; nt++) {
                short8 bf = *(const short8*)&xT[(nt * 16 + l15) * 520 + c0 + 8 * l4];
                acc[nt] = mfma16(af, bf, acc[nt]);
            }
        }

#pragma unroll
        for (int r = 0; r < 4; r++) {
            const int o_d = ot * 64 + w * 16 + 4 * l4 + r;
#pragma unroll
            for (int nt = 0; nt < 2; nt++) {
                const int n = n0 + nt * 16 + l15;
                const float val = acc[nt][r];
                if (o_d < 32) {
                    qT[((size_t)(b * 4096 + n)) * 32 + o_d] = f2bf(val + bq[o_d] * LOG2E);
                } else if (o_d < 64) {
                    const int s = n & 31;
                    const int p = 16 * ((s >> 2) & 1) + 4 * (s >> 3) + (s & 3);
                    const int nst = (n & ~31) | p;
                    kT[((size_t)(b * 4096 + nst)) * 32 + (o_d - 32)] = f2bf(val + bk[o_d - 32]);
                } else {
                    vm[((size_t)(b * 512 + (o_d - 64))) * 4096 + n] = f2bf(val + bv[o_d - 64]);
                }
            }
        }
    }
}

// ---------------- Flash attention + residual (R2 structure + prefetch/setprio) ----
// 256 blocks x 8 waves (512 thr). Block = (b, q-tile of 64); wave w covers
// c in [w*64, w*64+64). j-macro-tile = 256 (wave w produces j in [w*32,+32)),
// dbuf P 64 KB, one barrier per macro-tile. K loads for t+1 hoisted before
// CONSUME(t); setprio around the PV cluster. launch_bounds(512,1) frees VGPRs.
__global__ __launch_bounds__(512, 1) void attn_kernel(
    const short* __restrict__ qT, const short* __restrict__ kT,
    const short* __restrict__ vm, const float* __restrict__ x,
    const float* __restrict__ gamma, float* __restrict__ out)
{
    __shared__ short P_lds[2][32 * 512];   // [buf][frag = w*4+it][lane*8]
    __shared__ float red_lds[8][64];
    const int tid = threadIdx.x;
    const int lane = tid & 63;
    const int w = tid >> 6;
    const int l15 = lane & 15, l4 = lane >> 4;

    // XCD decode: b = xcd>>1 -> each batch pinned to 2 XCDs
    const int bid = blockIdx.x;
    const int xcd = bid & 7;
    const int idx = bid >> 3;            // 0..31
    const int b   = xcd >> 1;
    const int qt  = (xcd & 1) * 32 + idx;
    const int i0  = qt * 64;
    const int cb  = w * 64;

    short8 qf[4];
#pragma unroll
    for (int it = 0; it < 4; it++)
        qf[it] = *(const short8*)(qT + ((size_t)(b * 4096 + i0 + it * 16 + l15)) * 32 + 8 * l4);

    floatx4 acc[4][4];   // [ct][it]
#pragma unroll
    for (int ct = 0; ct < 4; ct++)
#pragma unroll
        for (int it = 0; it < 4; it++) acc[ct][it] = (floatx4)(0.0f);

    float l_[4] = {0.0f, 0.0f, 0.0f, 0.0f};

    const short* kb = kT + (size_t)b * 4096 * 32;
    const short* vb = vm + (size_t)b * 512 * 4096;

#define PROD(T, KF0, KF1)                                                            \
    {                                                                                \
        const int buf = (T) & 1;                                                     \
        _Pragma("unroll")                                                            \
        for (int it = 0; it < 4; it++) {                                             \
            floatx4 s0 = mfma16((KF0), qf[it], (floatx4)(0.0f));                     \
            floatx4 s1 = mfma16((KF1), qf[it], (floatx4)(0.0f));                     \
            float p[8];                                                              \
            _Pragma("unroll")                                                        \
            for (int r = 0; r < 4; r++) {                                            \
                p[r]     = __builtin_amdgcn_exp2f(s0[r]);                            \
                p[4 + r] = __builtin_amdgcn_exp2f(s1[r]);                            \
            }                                                                        \
            union { short8 s; unsigned u[4]; } pk;                                   \
            _Pragma("unroll")                                                        \
            for (int j2 = 0; j2 < 4; j2++) pk.u[j2] = cvt_pk_bf16(p[2*j2], p[2*j2+1]); \
            *(short8*)&P_lds[buf][(w * 4 + it) * 512 + lane * 8] = pk.s;             \
            l_[it] += ((p[0] + p[1]) + (p[2] + p[3])) + ((p[4] + p[5]) + (p[6] + p[7])); \
        }                                                                            \
    }

#define CONSUME(T)                                                                   \
    {                                                                                \
        const int buf = (T) & 1;                                                     \
        __builtin_amdgcn_s_setprio(1);                                               \
        _Pragma("unroll")                                                            \
        for (int jg = 0; jg < 8; jg++) {                                             \
            short8 pcf[4];                                                           \
            _Pragma("unroll")                                                        \
            for (int it = 0; it < 4; it++)                                           \
                pcf[it] = *(const short8*)&P_lds[buf][(jg * 4 + it) * 512 + lane * 8]; \
            _Pragma("unroll")                                                        \
            for (int ct = 0; ct < 4; ct++) {                                         \
                short8 vf = *(const short8*)(vb + (size_t)(cb + ct * 16 + l15) * 4096 \
                                             + (T) * 256 + jg * 32 + 8 * l4);        \
                _Pragma("unroll")                                                    \
                for (int it = 0; it < 4; it++)                                       \
                    acc[ct][it] = mfma16(vf, pcf[it], acc[ct][it]);                  \
            }                                                                        \
        }                                                                            \
        __builtin_amdgcn_s_setprio(0);                                               \
    }

    // prologue: produce macro-tile 0
    {
        short8 kf0 = *(const short8*)(kb + (size_t)(w * 32 + l15) * 32 + 8 * l4);
        short8 kf1 = *(const short8*)(kb + (size_t)(w * 32 + 16 + l15) * 32 + 8 * l4);
        PROD(0, kf0, kf1);
    }

#pragma unroll 1
    for (int t = 0; t < 16; t++) {
        __syncthreads();
        short8 nk0, nk1;
        if (t < 15) {   // hoist next K loads so their latency hides under CONSUME
            const int jj = (t + 1) * 256 + w * 32;
            nk0 = *(const short8*)(kb + (size_t)(jj + l15) * 32 + 8 * l4);
            nk1 = *(const short8*)(kb + (size_t)(jj + 16 + l15) * 32 + 8 * l4);
        }
        CONSUME(t);
        if (t < 15) PROD(t + 1, nk0, nk1);
    }
#undef PROD
#undef CONSUME

    // l: reduce within wave (over l4 groups), then across 8 waves via LDS
#pragma unroll
    for (int it = 0; it < 4; it++) {
        l_[it] += __shfl_xor(l_[it], 16, 64);
        l_[it] += __shfl_xor(l_[it], 32, 64);
    }
    if (lane < 16)
#pragma unroll
        for (int it = 0; it < 4; it++) red_lds[w][it * 16 + lane] = l_[it];
    __syncthreads();

    const float g = gamma[0];
    float inv[4];
#pragma unroll
    for (int it = 0; it < 4; it++) {
        float s = 0.0f;
#pragma unroll
        for (int ww = 0; ww < 8; ww++) s += red_lds[ww][it * 16 + l15];
        inv[it] = g / s;
    }

#pragma unroll
    for (int ct = 0; ct < 4; ct++)
#pragma unroll
        for (int it = 0; it < 4; it++)
#pragma unroll
            for (int r = 0; r < 4; r++) {
                const int c = cb + ct * 16 + 4 * l4 + r;
                const int i = i0 + it * 16 + l15;
                const size_t o = ((size_t)(b * 512 + c)) * 4096 + i;
                out[o] = acc[ct][it][r] * inv[it] + x[o];
            }
}

extern "C" void kernel_launch(void* const* d_in, const int* in_sizes, int n_in,
                              void* d_out, int out_size, void* d_ws, size_t ws_size,
                              hipStream_t stream) {
    const float* x     = (const float*)d_in[0];
    const float* wq    = (const float*)d_in[1];
    const float* bq    = (const float*)d_in[2];
    const float* wk    = (const float*)d_in[3];
    const float* bk    = (const float*)d_in[4];
    const float* wv    = (const float*)d_in[5];
    const float* bv    = (const float*)d_in[6];
    const float* gamma = (const float*)d_in[7];
    float* out = (float*)d_out;

    short* qT = (short*)d_ws;                  // 1 MB
    short* kT = qT + (size_t)4 * 4096 * 32;    // 1 MB
    short* vm = kT + (size_t)4 * 4096 * 32;    // 16 MB
    short* wb = vm + (size_t)4 * 512 * 4096;   // 0.56 MB

    wcvt_kernel<<<288, 256, 0, stream>>>(wq, wk, wv, wb);
    proj_kernel<<<dim3(128, 3, 4), 256, 0, stream>>>(x, wb, bq, bk, bv, qT, kT, vm);
    attn_kernel<<<256, 512, 0, stream>>>(qT, kT, vm, x, gamma, out);
}

// Round 9
// 196.534 us; speedup vs baseline: 1.9091x; 1.0283x over previous
//
#include <hip/hip_runtime.h>
#include <hip/hip_bf16.h>

#define LOG2E 1.44269504088896340736f

typedef __attribute__((ext_vector_type(8))) short short8;
typedef __attribute__((ext_vector_type(4))) float floatx4;

static __device__ __forceinline__ short f2bf(float f) {
    union { float f; unsigned u; } v; v.f = f;
    unsigned r = (v.u + 0x7FFF + ((v.u >> 16) & 1)) >> 16;  // RNE
    return (short)r;
}

static __device__ __forceinline__ floatx4 mfma16(short8 a, short8 b, floatx4 c) {
    return __builtin_amdgcn_mfma_f32_16x16x32_bf16(a, b, c, 0, 0, 0);
}

static __device__ __forceinline__ unsigned cvt_pk_bf16(float lo, float hi) {
    unsigned u;
    asm("v_cvt_pk_bf16_f32 %0, %1, %2" : "=v"(u) : "v"(lo), "v"(hi));
    return u;
}

// ---------------- Weight pre-convert: wb[576][512] bf16 ----------------
__global__ __launch_bounds__(256) void wcvt_kernel(
    const float* __restrict__ wq, const float* __restrict__ wk,
    const float* __restrict__ wv, short* __restrict__ wb)
{
    const int idx = (blockIdx.x * 256 + threadIdx.x) * 4;
    const int row = idx >> 9;
    const int col = idx & 511;
    const float* src;
    float sc = 1.0f;
    if (row < 32)      { src = wq + (size_t)row * 512; sc = LOG2E; }
    else if (row < 64) { src = wk + (size_t)(row - 32) * 512; }
    else               { src = wv + (size_t)(row - 64) * 512; }
    floatx4 v = *(const floatx4*)(src + col);
    union { short s[4]; long long ll; } o;
#pragma unroll
    for (int u = 0; u < 4; u++) o.s[u] = f2bf(v[u] * sc);
    *(long long*)(wb + idx) = o.ll;
}

// ---------------- Projection: x read ONCE ----------------
// grid (128 n-tiles of 32, B), block 256 (4 waves), LDS 33 KB. Each block
// stages its x tile once (packed b32 writes) and computes all 9 o-tiles.
__global__ __launch_bounds__(256) void proj_kernel(
    const float* __restrict__ x, const short* __restrict__ wb,
    const float* __restrict__ bq, const float* __restrict__ bk,
    const float* __restrict__ bv,
    short* __restrict__ qT, short* __restrict__ kT, short* __restrict__ vm)
{
    __shared__ short xT[32 * 520];   // [n][c] bf16, pitch 520
    const int tid = threadIdx.x;
    const int w = tid >> 6;
    const int lane = tid & 63;
    const int l15 = lane & 15, l4 = lane >> 4;
    const int n0 = blockIdx.x * 32;
    const int b  = blockIdx.y;

    const float* xb = x + (size_t)b * 512 * 4096;

    // staging: thread = (c-pair cp, n-quad nq); 8 iters; cvt_pk -> b32 writes
    const int cp = tid >> 3;          // 0..31
    const int nq = (tid & 7) * 4;     // 0,4,..,28
#pragma unroll
    for (int p = 0; p < 8; p++) {
        const int c = (p * 32 + cp) * 2;
        const float* r0 = xb + (size_t)c * 4096 + n0 + nq;
        const float* r1 = r0 + 4096;
        floatx4 xa = *(const floatx4*)r0;
        floatx4 xc = *(const floatx4*)r1;
#pragma unroll
        for (int u = 0; u < 4; u++)
            *(unsigned*)&xT[(nq + u) * 520 + c] = cvt_pk_bf16(xa[u], xc[u]);
    }
    __syncthreads();

#pragma unroll 1
    for (int ot = 0; ot < 9; ot++) {
        const short* wrow = wb + (size_t)(ot * 64 + w * 16 + l15) * 512;
        floatx4 acc[2];
#pragma unroll
        for (int i = 0; i < 2; i++) acc[i] = (floatx4)(0.0f);

#pragma unroll 4
        for (int c0 = 0; c0 < 512; c0 += 32) {
            short8 af = *(const short8*)(wrow + c0 + 8 * l4);
#pragma unroll
            for (int nt = 0; nt < 2; nt++) {
                short8 bf = *(const short8*)&xT[(nt * 16 + l15) * 520 + c0 + 8 * l4];
                acc[nt] = mfma16(af, bf, acc[nt]);
            }
        }

#pragma unroll
        for (int r = 0; r < 4; r++) {
            const int o_d = ot * 64 + w * 16 + 4 * l4 + r;
#pragma unroll
            for (int nt = 0; nt < 2; nt++) {
                const int n = n0 + nt * 16 + l15;
                const float val = acc[nt][r];
                if (o_d < 32) {
                    qT[((size_t)(b * 4096 + n)) * 32 + o_d] = f2bf(val + bq[o_d] * LOG2E);
                } else if (o_d < 64) {
                    const int s = n & 31;
                    const int p2 = 16 * ((s >> 2) & 1) + 4 * (s >> 3) + (s & 3);
                    const int nst = (n & ~31) | p2;
                    kT[((size_t)(b * 4096 + nst)) * 32 + (o_d - 32)] = f2bf(val + bk[o_d - 32]);
                } else {
                    vm[((size_t)(b * 512 + (o_d - 64))) * 4096 + n] = f2bf(val + bv[o_d - 64]);
                }
            }
        }
    }
}

// ---------------- Flash attention + residual ----------------
// R7 structure (256 blocks x 8 waves, QBLK=64, j-macro=256, dbuf P 64 KB)
// + deep software pipeline in CONSUME: V frags triple-buffered (jg+2 ahead,
// 8-12 loads in flight), P frags double-buffered (jg+1 ahead).
__global__ __launch_bounds__(512, 1) void attn_kernel(
    const short* __restrict__ qT, const short* __restrict__ kT,
    const short* __restrict__ vm, const float* __restrict__ x,
    const float* __restrict__ gamma, float* __restrict__ out)
{
    __shared__ short P_lds[2][32 * 512];   // [buf][frag = w*4+it][lane*8]
    __shared__ float red_lds[8][64];
    const int tid = threadIdx.x;
    const int lane = tid & 63;
    const int w = tid >> 6;
    const int l15 = lane & 15, l4 = lane >> 4;

    const int bid = blockIdx.x;
    const int xcd = bid & 7;
    const int idx = bid >> 3;            // 0..31
    const int b   = xcd >> 1;
    const int qt  = (xcd & 1) * 32 + idx;
    const int i0  = qt * 64;
    const int cb  = w * 64;

    short8 qf[4];
#pragma unroll
    for (int it = 0; it < 4; it++)
        qf[it] = *(const short8*)(qT + ((size_t)(b * 4096 + i0 + it * 16 + l15)) * 32 + 8 * l4);

    floatx4 acc[4][4];   // [ct][it]
#pragma unroll
    for (int ct = 0; ct < 4; ct++)
#pragma unroll
        for (int it = 0; it < 4; it++) acc[ct][it] = (floatx4)(0.0f);

    float l_[4] = {0.0f, 0.0f, 0.0f, 0.0f};

    const short* kb = kT + (size_t)b * 4096 * 32;
    const short* vb = vm + (size_t)b * 512 * 4096;

#define PROD(T, KF0, KF1)                                                            \
    {                                                                                \
        const int buf = (T) & 1;                                                     \
        _Pragma("unroll")                                                            \
        for (int it = 0; it < 4; it++) {                                             \
            floatx4 s0 = mfma16((KF0), qf[it], (floatx4)(0.0f));                     \
            floatx4 s1 = mfma16((KF1), qf[it], (floatx4)(0.0f));                     \
            float p[8];                                                              \
            _Pragma("unroll")                                                        \
            for (int r = 0; r < 4; r++) {                                            \
                p[r]     = __builtin_amdgcn_exp2f(s0[r]);                            \
                p[4 + r] = __builtin_amdgcn_exp2f(s1[r]);                            \
            }                                                                        \
            union { short8 s; unsigned u[4]; } pk;                                   \
            _Pragma("unroll")                                                        \
            for (int j2 = 0; j2 < 4; j2++) pk.u[j2] = cvt_pk_bf16(p[2*j2], p[2*j2+1]); \
            *(short8*)&P_lds[buf][(w * 4 + it) * 512 + lane * 8] = pk.s;             \
            l_[it] += ((p[0] + p[1]) + (p[2] + p[3])) + ((p[4] + p[5]) + (p[6] + p[7])); \
        }                                                                            \
    }

#define VLOAD(T, JG, CT)                                                             \
    (*(const short8*)(vb + (size_t)(cb + (CT) * 16 + l15) * 4096 + (T) * 256 + (JG) * 32 + 8 * l4))
#define PREAD(BUF, JG, IT)                                                           \
    (*(const short8*)&P_lds[BUF][((JG) * 4 + (IT)) * 512 + lane * 8])

#define CONSUME(T)                                                                   \
    {                                                                                \
        const int buf = (T) & 1;                                                     \
        short8 vfp[3][4];                                                            \
        short8 pcp[2][4];                                                            \
        _Pragma("unroll")                                                            \
        for (int ct = 0; ct < 4; ct++) vfp[0][ct] = VLOAD(T, 0, ct);                 \
        _Pragma("unroll")                                                            \
        for (int ct = 0; ct < 4; ct++) vfp[1][ct] = VLOAD(T, 1, ct);                 \
        _Pragma("unroll")                                                            \
        for (int it = 0; it < 4; it++) pcp[0][it] = PREAD(buf, 0, it);               \
        _Pragma("unroll")                                                            \
        for (int jg = 0; jg < 8; jg++) {                                             \
            if (jg < 6) {                                                            \
                _Pragma("unroll")                                                    \
                for (int ct = 0; ct < 4; ct++)                                       \
                    vfp[(jg + 2) % 3][ct] = VLOAD(T, jg + 2, ct);                    \
            }                                                                        \
            if (jg < 7) {                                                            \
                _Pragma("unroll")                                                    \
                for (int it = 0; it < 4; it++)                                       \
                    pcp[(jg + 1) & 1][it] = PREAD(buf, jg + 1, it);                  \
            }                                                                        \
            __builtin_amdgcn_s_setprio(1);                                           \
            _Pragma("unroll")                                                        \
            for (int ct = 0; ct < 4; ct++)                                           \
                _Pragma("unroll")                                                    \
                for (int it = 0; it < 4; it++)                                       \
                    acc[ct][it] = mfma16(vfp[jg % 3][ct], pcp[jg & 1][it], acc[ct][it]); \
            __builtin_amdgcn_s_setprio(0);                                           \
        }                                                                            \
    }

    // prologue: produce macro-tile 0
    {
        short8 kf0 = *(const short8*)(kb + (size_t)(w * 32 + l15) * 32 + 8 * l4);
        short8 kf1 = *(const short8*)(kb + (size_t)(w * 32 + 16 + l15) * 32 + 8 * l4);
        PROD(0, kf0, kf1);
    }

#pragma unroll 1
    for (int t = 0; t < 16; t++) {
        __syncthreads();
        short8 nk0, nk1;
        if (t < 15) {   // hoist next K loads; latency hides under CONSUME
            const int jj = (t + 1) * 256 + w * 32;
            nk0 = *(const short8*)(kb + (size_t)(jj + l15) * 32 + 8 * l4);
            nk1 = *(const short8*)(kb + (size_t)(jj + 16 + l15) * 32 + 8 * l4);
        }
        CONSUME(t);
        if (t < 15) PROD(t + 1, nk0, nk1);
    }
#undef PROD
#undef CONSUME
#undef VLOAD
#undef PREAD

    // l: reduce within wave, then across 8 waves via LDS
#pragma unroll
    for (int it = 0; it < 4; it++) {
        l_[it] += __shfl_xor(l_[it], 16, 64);
        l_[it] += __shfl_xor(l_[it], 32, 64);
    }
    if (lane < 16)
#pragma unroll
        for (int it = 0; it < 4; it++) red_lds[w][it * 16 + lane] = l_[it];
    __syncthreads();

    const float g = gamma[0];
    float inv[4];
#pragma unroll
    for (int it = 0; it < 4; it++) {
        float s = 0.0f;
#pragma unroll
        for (int ww = 0; ww < 8; ww++) s += red_lds[ww][it * 16 + l15];
        inv[it] = g / s;
    }

#pragma unroll
    for (int ct = 0; ct < 4; ct++)
#pragma unroll
        for (int it = 0; it < 4; it++)
#pragma unroll
            for (int r = 0; r < 4; r++) {
                const int c = cb + ct * 16 + 4 * l4 + r;
                const int i = i0 + it * 16 + l15;
                const size_t o = ((size_t)(b * 512 + c)) * 4096 + i;
                out[o] = acc[ct][it][r] * inv[it] + x[o];
            }
}

extern "C" void kernel_launch(void* const* d_in, const int* in_sizes, int n_in,
                              void* d_out, int out_size, void* d_ws, size_t ws_size,
                              hipStream_t stream) {
    const float* x     = (const float*)d_in[0];
    const float* wq    = (const float*)d_in[1];
    const float* bq    = (const float*)d_in[2];
    const float* wk    = (const float*)d_in[3];
    const float* bk    = (const float*)d_in[4];
    const float* wv    = (const float*)d_in[5];
    const float* bv    = (const float*)d_in[6];
    const float* gamma = (const float*)d_in[7];
    float* out = (float*)d_out;

    short* qT = (short*)d_ws;                  // 1 MB
    short* kT = qT + (size_t)4 * 4096 * 32;    // 1 MB
    short* vm = kT + (size_t)4 * 4096 * 32;    // 16 MB
    short* wb = vm + (size_t)4 * 512 * 4096;   // 0.56 MB

    wcvt_kernel<<<288, 256, 0, stream>>>(wq, wk, wv, wb);
    proj_kernel<<<dim3(128, 4), 256, 0, stream>>>(x, wb, bq, bk, bv, qT, kT, vm);
    attn_kernel<<<256, 512, 0, stream>>>(qT, kT, vm, x, gamma, out);
}

// Round 10
// 133.870 us; speedup vs baseline: 2.8027x; 1.4681x over previous
//
#include <hip/hip_runtime.h>
#include <hip/hip_bf16.h>

#define LOG2E 1.44269504088896340736f

typedef __attribute__((ext_vector_type(8))) short short8;
typedef __attribute__((ext_vector_type(4))) float floatx4;

static __device__ __forceinline__ short f2bf(float f) {
    union { float f; unsigned u; } v; v.f = f;
    unsigned r = (v.u + 0x7FFF + ((v.u >> 16) & 1)) >> 16;  // RNE
    return (short)r;
}

static __device__ __forceinline__ floatx4 mfma16(short8 a, short8 b, floatx4 c) {
    return __builtin_amdgcn_mfma_f32_16x16x32_bf16(a, b, c, 0, 0, 0);
}

static __device__ __forceinline__ unsigned cvt_pk_bf16(float lo, float hi) {
    unsigned u;
    asm("v_cvt_pk_bf16_f32 %0, %1, %2" : "=v"(u) : "v"(lo), "v"(hi));
    return u;
}

// ---------------- Weight pre-convert: wb tiled [(ot*16+cg)][64 o][32 c] ----------------
// rows 0-31 = wq * LOG2E, 32-63 = wk, 64-575 = wv. Tiled so proj's A-fragment
// load (16 o-rows x 32 c) is one contiguous 1KB per instruction.
__global__ __launch_bounds__(256) void wcvt_kernel(
    const float* __restrict__ wq, const float* __restrict__ wk,
    const float* __restrict__ wv, short* __restrict__ wb)
{
    const int idx = (blockIdx.x * 256 + threadIdx.x) * 4;   // 294912 total
    const int row = idx >> 9;          // 0..575
    const int col = idx & 511;
    const float* src;
    float sc = 1.0f;
    if (row < 32)      { src = wq + (size_t)row * 512; sc = LOG2E; }
    else if (row < 64) { src = wk + (size_t)(row - 32) * 512; }
    else               { src = wv + (size_t)(row - 64) * 512; }
    floatx4 v = *(const floatx4*)(src + col);
    union { short s[4]; long long ll; } o;
#pragma unroll
    for (int u = 0; u < 4; u++) o.s[u] = f2bf(v[u] * sc);
    // tiled dest: tile = (row/64)*16 + col/32 ; within: (row&63)*32 + (col&31)
    const int didx = (((row >> 6) * 16 + (col >> 5)) * 64 + (row & 63)) * 32 + (col & 31);
    *(long long*)(wb + didx) = o.ll;
}

// ---------------- Projection: x read ONCE; W reads contiguous ----------------
// grid (128 n-tiles of 32, B), block 256 (4 waves), LDS 33 KB.
// v output TILED: vm[b][n>>5][c][n&31] so attn's V loads are contiguous.
__global__ __launch_bounds__(256) void proj_kernel(
    const float* __restrict__ x, const short* __restrict__ wb,
    const float* __restrict__ bq, const float* __restrict__ bk,
    const float* __restrict__ bv,
    short* __restrict__ qT, short* __restrict__ kT, short* __restrict__ vm)
{
    __shared__ short xT[32 * 520];   // [n][c] bf16, pitch 520
    const int tid = threadIdx.x;
    const int w = tid >> 6;
    const int lane = tid & 63;
    const int l15 = lane & 15, l4 = lane >> 4;
    const int n0 = blockIdx.x * 32;
    const int b  = blockIdx.y;

    const float* xb = x + (size_t)b * 512 * 4096;

    // staging: thread = (c-pair, n-quad); cvt_pk -> b32 LDS writes
    const int cp = tid >> 3;          // 0..31
    const int nq = (tid & 7) * 4;     // 0,4,..,28
#pragma unroll
    for (int p = 0; p < 8; p++) {
        const int c = (p * 32 + cp) * 2;
        const float* r0 = xb + (size_t)c * 4096 + n0 + nq;
        const float* r1 = r0 + 4096;
        floatx4 xa = *(const floatx4*)r0;
        floatx4 xc = *(const floatx4*)r1;
#pragma unroll
        for (int u = 0; u < 4; u++)
            *(unsigned*)&xT[(nq + u) * 520 + c] = cvt_pk_bf16(xa[u], xc[u]);
    }
    __syncthreads();

#pragma unroll 1
    for (int ot = 0; ot < 9; ot++) {
        floatx4 acc[2];
#pragma unroll
        for (int i = 0; i < 2; i++) acc[i] = (floatx4)(0.0f);

#pragma unroll 4
        for (int c0 = 0; c0 < 512; c0 += 32) {
            // contiguous tiled W read: 1KB per instruction
            short8 af = *(const short8*)(wb + ((size_t)(ot * 16 + (c0 >> 5)) * 64
                                               + w * 16 + l15) * 32 + 8 * l4);
#pragma unroll
            for (int nt = 0; nt < 2; nt++) {
                short8 bf = *(const short8*)&xT[(nt * 16 + l15) * 520 + c0 + 8 * l4];
                acc[nt] = mfma16(af, bf, acc[nt]);
            }
        }

#pragma unroll
        for (int r = 0; r < 4; r++) {
            const int o_d = ot * 64 + w * 16 + 4 * l4 + r;
#pragma unroll
            for (int nt = 0; nt < 2; nt++) {
                const int n = n0 + nt * 16 + l15;
                const float val = acc[nt][r];
                if (o_d < 32) {
                    qT[((size_t)(b * 4096 + n)) * 32 + o_d] = f2bf(val + bq[o_d] * LOG2E);
                } else if (o_d < 64) {
                    const int s = n & 31;
                    const int p2 = 16 * ((s >> 2) & 1) + 4 * (s >> 3) + (s & 3);
                    const int nst = (n & ~31) | p2;
                    kT[((size_t)(b * 4096 + nst)) * 32 + (o_d - 32)] = f2bf(val + bk[o_d - 32]);
                } else {
                    // tiled V: [b][n>>5][c][n&31]; n>>5 == blockIdx.x here
                    const int c = o_d - 64;
                    vm[((size_t)((b * 128 + blockIdx.x) * 512 + c)) * 32
                       + (nt * 16 + l15)] = f2bf(val + bv[c]);
                }
            }
        }
    }
}

// ---------------- Flash attention + residual ----------------
// R8 structure (256 blocks x 8 waves, QBLK=64, j-macro=256, dbuf P 64 KB,
// pipelined CONSUME, setprio) with TILED V loads: each V fragment load is
// one contiguous 1KB -> no 64B-segment scatter, streams at full L2 BW.
__global__ __launch_bounds__(512, 1) void attn_kernel(
    const short* __restrict__ qT, const short* __restrict__ kT,
    const short* __restrict__ vm, const float* __restrict__ x,
    const float* __restrict__ gamma, float* __restrict__ out)
{
    __shared__ short P_lds[2][32 * 512];   // [buf][frag = w*4+it][lane*8]
    __shared__ float red_lds[8][64];
    const int tid = threadIdx.x;
    const int lane = tid & 63;
    const int w = tid >> 6;
    const int l15 = lane & 15, l4 = lane >> 4;

    const int bid = blockIdx.x;
    const int xcd = bid & 7;
    const int idx = bid >> 3;            // 0..31
    const int b   = xcd >> 1;
    const int qt  = (xcd & 1) * 32 + idx;
    const int i0  = qt * 64;
    const int cb  = w * 64;

    short8 qf[4];
#pragma unroll
    for (int it = 0; it < 4; it++)
        qf[it] = *(const short8*)(qT + ((size_t)(b * 4096 + i0 + it * 16 + l15)) * 32 + 8 * l4);

    floatx4 acc[4][4];   // [ct][it]
#pragma unroll
    for (int ct = 0; ct < 4; ct++)
#pragma unroll
        for (int it = 0; it < 4; it++) acc[ct][it] = (floatx4)(0.0f);

    float l_[4] = {0.0f, 0.0f, 0.0f, 0.0f};

    const short* kb = kT + (size_t)b * 4096 * 32;
    const short* vb = vm + (size_t)b * 512 * 4096;   // tiled [jt][512][32]

#define PROD(T, KF0, KF1)                                                            \
    {                                                                                \
        const int buf = (T) & 1;                                                     \
        _Pragma("unroll")                                                            \
        for (int it = 0; it < 4; it++) {                                             \
            floatx4 s0 = mfma16((KF0), qf[it], (floatx4)(0.0f));                     \
            floatx4 s1 = mfma16((KF1), qf[it], (floatx4)(0.0f));                     \
            float p[8];                                                              \
            _Pragma("unroll")                                                        \
            for (int r = 0; r < 4; r++) {                                            \
                p[r]     = __builtin_amdgcn_exp2f(s0[r]);                            \
                p[4 + r] = __builtin_amdgcn_exp2f(s1[r]);                            \
            }                                                                        \
            union { short8 s; unsigned u[4]; } pk;                                   \
            _Pragma("unroll")                                                        \
            for (int j2 = 0; j2 < 4; j2++) pk.u[j2] = cvt_pk_bf16(p[2*j2], p[2*j2+1]); \
            *(short8*)&P_lds[buf][(w * 4 + it) * 512 + lane * 8] = pk.s;             \
            l_[it] += ((p[0] + p[1]) + (p[2] + p[3])) + ((p[4] + p[5]) + (p[6] + p[7])); \
        }                                                                            \
    }

// tiled V fragment: jt = T*8+JG; contiguous 1KB per instruction
#define VLOAD(T, JG, CT)                                                             \
    (*(const short8*)(vb + ((size_t)(((T) * 8 + (JG)) * 512 + cb + (CT) * 16 + l15)) * 32 + 8 * l4))
#define PREAD(BUF, JG, IT)                                                           \
    (*(const short8*)&P_lds[BUF][((JG) * 4 + (IT)) * 512 + lane * 8])

#define CONSUME(T)                                                                   \
    {                                                                                \
        const int buf = (T) & 1;                                                     \
        short8 vfp[3][4];                                                            \
        short8 pcp[2][4];                                                            \
        _Pragma("unroll")                                                            \
        for (int ct = 0; ct < 4; ct++) vfp[0][ct] = VLOAD(T, 0, ct);                 \
        _Pragma("unroll")                                                            \
        for (int ct = 0; ct < 4; ct++) vfp[1][ct] = VLOAD(T, 1, ct);                 \
        _Pragma("unroll")                                                            \
        for (int it = 0; it < 4; it++) pcp[0][it] = PREAD(buf, 0, it);               \
        _Pragma("unroll")                                                            \
        for (int jg = 0; jg < 8; jg++) {                                             \
            if (jg < 6) {                                                            \
                _Pragma("unroll")                                                    \
                for (int ct = 0; ct < 4; ct++)                                       \
                    vfp[(jg + 2) % 3][ct] = VLOAD(T, jg + 2, ct);                    \
            }                                                                        \
            if (jg < 7) {                                                            \
                _Pragma("unroll")                                                    \
                for (int it = 0; it < 4; it++)                                       \
                    pcp[(jg + 1) & 1][it] = PREAD(buf, jg + 1, it);                  \
            }                                                                        \
            __builtin_amdgcn_s_setprio(1);                                           \
            _Pragma("unroll")                                                        \
            for (int ct = 0; ct < 4; ct++)                                           \
                _Pragma("unroll")                                                    \
                for (int it = 0; it < 4; it++)                                       \
                    acc[ct][it] = mfma16(vfp[jg % 3][ct], pcp[jg & 1][it], acc[ct][it]); \
            __builtin_amdgcn_s_setprio(0);                                           \
        }                                                                            \
    }

    // prologue: produce macro-tile 0
    {
        short8 kf0 = *(const short8*)(kb + (size_t)(w * 32 + l15) * 32 + 8 * l4);
        short8 kf1 = *(const short8*)(kb + (size_t)(w * 32 + 16 + l15) * 32 + 8 * l4);
        PROD(0, kf0, kf1);
    }

#pragma unroll 1
    for (int t = 0; t < 16; t++) {
        __syncthreads();
        short8 nk0, nk1;
        if (t < 15) {   // hoist next K loads; latency hides under CONSUME
            const int jj = (t + 1) * 256 + w * 32;
            nk0 = *(const short8*)(kb + (size_t)(jj + l15) * 32 + 8 * l4);
            nk1 = *(const short8*)(kb + (size_t)(jj + 16 + l15) * 32 + 8 * l4);
        }
        CONSUME(t);
        if (t < 15) PROD(t + 1, nk0, nk1);
    }
#undef PROD
#undef CONSUME
#undef VLOAD
#undef PREAD

    // l: reduce within wave, then across 8 waves via LDS
#pragma unroll
    for (int it = 0; it < 4; it++) {
        l_[it] += __shfl_xor(l_[it], 16, 64);
        l_[it] += __shfl_xor(l_[it], 32, 64);
    }
    if (lane < 16)
#pragma unroll
        for (int it = 0; it < 4; it++) red_lds[w][it * 16 + lane] = l_[it];
    __syncthreads();

    const float g = gamma[0];
    float inv[4];
#pragma unroll
    for (int it = 0; it < 4; it++) {
        float s = 0.0f;
#pragma unroll
        for (int ww = 0; ww < 8; ww++) s += red_lds[ww][it * 16 + l15];
        inv[it] = g / s;
    }

#pragma unroll
    for (int ct = 0; ct < 4; ct++)
#pragma unroll
        for (int it = 0; it < 4; it++)
#pragma unroll
            for (int r = 0; r < 4; r++) {
                const int c = cb + ct * 16 + 4 * l4 + r;
                const int i = i0 + it * 16 + l15;
                const size_t o = ((size_t)(b * 512 + c)) * 4096 + i;
                out[o] = acc[ct][it][r] * inv[it] + x[o];
            }
}

extern "C" void kernel_launch(void* const* d_in, const int* in_sizes, int n_in,
                              void* d_out, int out_size, void* d_ws, size_t ws_size,
                              hipStream_t stream) {
    const float* x     = (const float*)d_in[0];
    const float* wq    = (const float*)d_in[1];
    const float* bq    = (const float*)d_in[2];
    const float* wk    = (const float*)d_in[3];
    const float* bk    = (const float*)d_in[4];
    const float* wv    = (const float*)d_in[5];
    const float* bv    = (const float*)d_in[6];
    const float* gamma = (const float*)d_in[7];
    float* out = (float*)d_out;

    short* qT = (short*)d_ws;                  // 1 MB
    short* kT = qT + (size_t)4 * 4096 * 32;    // 1 MB
    short* vm = kT + (size_t)4 * 4096 * 32;    // 16 MB (tiled [b][jt][512][32])
    short* wb = vm + (size_t)4 * 512 * 4096;   // 0.56 MB (tiled)

    wcvt_kernel<<<288, 256, 0, stream>>>(wq, wk, wv, wb);
    proj_kernel<<<dim3(128, 4), 256, 0, stream>>>(x, wb, bq, bk, bv, qT, kT, vm);
    attn_kernel<<<256, 512, 0, stream>>>(qT, kT, vm, x, gamma, out);
}